// Round 23
// baseline (343.356 us; speedup 1.0000x reference)
//
#include <hip/hip_runtime.h>
#include <stdint.h>

typedef __bf16 bf16;
typedef __bf16 bf16x8 __attribute__((ext_vector_type(8)));
typedef __bf16 bf16x4 __attribute__((ext_vector_type(4)));
typedef float f32x4 __attribute__((ext_vector_type(4)));

__device__ inline void gload_lds16(const void* g, void* l) {
  __builtin_amdgcn_global_load_lds(
      (__attribute__((address_space(1))) void*)g,
      (__attribute__((address_space(3))) void*)l, 16, 0, 0);
}

// XCD-aware bijective swizzle (T1).  Requires nwg % 8 == 0.
__device__ inline void xcd_swizzle(int& bx, int& by, int& bz) {
  const int gx = gridDim.x, gy = gridDim.y;
  int lin = blockIdx.x + gx * (blockIdx.y + gy * blockIdx.z);
  const int nwg = gx * gy * gridDim.z;
  lin = (lin & 7) * (nwg >> 3) + (lin >> 3);
  bx = lin % gx;
  const int tmp = lin / gx;
  by = tmp % gy;
  bz = tmp / gy;
}

// ---------------- fp32 -> bf16 conversion ----------------
// xb2: [8192][2048] bf16.  Cols 0-1023: x rows (XCD-aligned ownership).
// Cols 1024-2047: W row j (packed [Wq;Wk;Wv], j<3072) interleaved.
__global__ __launch_bounds__(256) void cvt_all(
    const float* __restrict__ x, const float* __restrict__ wq,
    const float* __restrict__ wk, const float* __restrict__ wv,
    bf16* __restrict__ xb2) {
  const int b = blockIdx.x;
  const int t = threadIdx.x;
  const int xcd = b & 7, j = b >> 3;
#pragma unroll
  for (int k = 0; k < 4; ++k) {
    const int row = xcd * 1024 + j + 256 * k;
    float4 v = ((const float4*)x)[(long)row * 256 + t];
    bf16x4 o;
    o[0] = (bf16)v.x; o[1] = (bf16)v.y; o[2] = (bf16)v.z; o[3] = (bf16)v.w;
    *(bf16x4*)(xb2 + ((long)row << 11) + t * 4) = o;
  }
  for (long p = (long)b * 256 + t; p < 786432; p += 524288) {
    const int w = (int)(p >> 18);
    const int off = (int)(p & 262143);
    const float* src = (w == 0) ? wq : ((w == 1) ? wk : wv);
    const int row = off >> 8, c4 = off & 255;
    float4 v = ((const float4*)src)[off];
    bf16x4 o;
    o[0] = (bf16)v.x; o[1] = (bf16)v.y; o[2] = (bf16)v.z; o[3] = (bf16)v.w;
    *(bf16x4*)(xb2 + ((long)(w * 1024 + row) << 11) + 1024 + c4 * 4) = o;
  }
}

// =====================================================================
// gemm8b: BM=256, BN=256, BK=32, 512 threads (8 waves 2Mx4N, wave-tile
// 128x64, B-frag cache), LDS 64K -> 2 BLOCKS/CU (16 waves/CU).
// 2 phases/tile, counted vmcnt(2) once/tile (never 0), single barrier/
// phase, XCD-swizzled.  bf16 out + scale.  TLP experiment for projQK.
// Region layout (16K each: A rows 0-255, B rows 0-255 of 32 cols):
//   16B unit (r, cs): holds row r, k-chunk cs^(r&3)  (cs = stored chunk).
//   Frag read: addr = r*64 + ((kch^(fr&3))<<4)  — balanced 2-way banks.
//   Staging: thread tid, rd -> row rd*128+(tid>>2), k=((tid&3)^((tid>>2)&3))*8.
// Liveness: A[c] freed at its tile's P2 barrier; B[c] freed at P1 barrier.
//   P1 stages A(t+1)->nb (free since t-1.P2);  P2 stages B(t+2)->cur.
//   vmcnt(2) at P2 end: next tile's A+B complete, newest B(t+2) in flight.
// =====================================================================
__global__ __launch_bounds__(512, 4) void gemm8b(
    const bf16* __restrict__ Ag, const bf16* __restrict__ Bg,
    bf16* __restrict__ Cg,
    long lda, long ldb, long ldc,
    long sA, long sB, long sC, int K, float scale)
{
  constexpr int BUFSZ = 32768;
  __shared__ alignas(16) char lds[2 * BUFSZ];
  int bx, by, bz;
  xcd_swizzle(bx, by, bz);
  const int tid = threadIdx.x;
  const int l = tid & 63;
  const int wv = tid >> 6;
  const int wm = wv >> 2;
  const int wn = wv & 3;
  const int fr = l & 15;
  const int kch = l >> 4;
  const int m0 = by * 256;
  const int n0 = bx * 256;
  const bf16* Ab = Ag + (long)bz * sA;
  const bf16* Bb = Bg + (long)bz * sB;

  const int swz = (kch ^ (fr & 3)) << 4;
  const int a_base = wm * 8192 + fr * 64 + swz;           // + m*1024, m=0..7
  const int b_base = 16384 + wn * 4096 + fr * 64 + swz;   // + n*1024, n=0..3

  const int s_row = tid >> 2;                              // + rd*128
  const int s_k = ((tid & 3) ^ ((tid >> 2) & 3)) * 8;
  const int wb16 = (tid & 448) * 16;

  const int NT = K >> 5;
  f32x4 acc[8][4] = {};

  auto stageA = [&](int tile, int buf) {
#pragma unroll
    for (int rd = 0; rd < 2; ++rd)
      gload_lds16(Ab + (long)(m0 + rd * 128 + s_row) * lda + tile * 32 + s_k,
                  lds + buf * BUFSZ + rd * 8192 + wb16);
  };
  auto stageB = [&](int tile, int buf) {
#pragma unroll
    for (int rd = 0; rd < 2; ++rd)
      gload_lds16(Bb + (long)(n0 + rd * 128 + s_row) * ldb + tile * 32 + s_k,
                  lds + buf * BUFSZ + 16384 + rd * 8192 + wb16);
  };

  // prologue: tiles 0,1 fully staged; wait tile 0 (A1,B1 stay in flight)
  stageA(0, 0); stageB(0, 0);
  stageA(min(1, NT - 1), 1); stageB(min(1, NT - 1), 1);
  asm volatile("s_waitcnt vmcnt(4)" ::: "memory");
  __builtin_amdgcn_sched_barrier(0);
  __builtin_amdgcn_s_barrier();

  for (int t = 0; t < NT; ++t) {
    const int cur = t & 1;
    const int nb = cur ^ 1;
    const char* bufA = lds + cur * BUFSZ;
    const int t1 = min(t + 1, NT - 1);
    const int t2 = min(t + 2, NT - 1);

    bf16x8 bfg[4], af[4];
    // P1: stage A(t+1)->nb; read B (all, cached) + A m0..3; MFMA; barrier
    stageA(t1, nb);
#pragma unroll
    for (int n = 0; n < 4; ++n) bfg[n] = *(const bf16x8*)(bufA + b_base + n * 1024);
#pragma unroll
    for (int m = 0; m < 4; ++m) af[m] = *(const bf16x8*)(bufA + a_base + m * 1024);
    __builtin_amdgcn_s_setprio(1);
#pragma unroll
    for (int m = 0; m < 4; ++m)
#pragma unroll
      for (int n = 0; n < 4; ++n)
        acc[m][n] = __builtin_amdgcn_mfma_f32_16x16x32_bf16(af[m], bfg[n], acc[m][n], 0, 0, 0);
    __builtin_amdgcn_s_setprio(0);
    __builtin_amdgcn_s_barrier();
    // P2: stage B(t+2)->cur (B[cur] freed at P1 barrier); read A m4..7;
    //     MFMA; vmcnt(2); barrier
    stageB(t2, cur);
#pragma unroll
    for (int m = 0; m < 4; ++m) af[m] = *(const bf16x8*)(bufA + a_base + (4 + m) * 1024);
    __builtin_amdgcn_s_setprio(1);
#pragma unroll
    for (int m = 0; m < 4; ++m)
#pragma unroll
      for (int n = 0; n < 4; ++n)
        acc[4 + m][n] = __builtin_amdgcn_mfma_f32_16x16x32_bf16(af[m], bfg[n], acc[4 + m][n], 0, 0, 0);
    __builtin_amdgcn_s_setprio(0);
    asm volatile("s_waitcnt vmcnt(2)" ::: "memory");
    __builtin_amdgcn_sched_barrier(0);
    __builtin_amdgcn_s_barrier();
  }
  asm volatile("s_waitcnt vmcnt(0)" ::: "memory");

  // epilogue: C/D layout col=lane&15, row=(lane>>4)*4+reg
#pragma unroll
  for (int mf = 0; mf < 8; ++mf) {
    const int row = m0 + wm * 128 + mf * 16 + (l >> 4) * 4;
#pragma unroll
    for (int n = 0; n < 4; ++n) {
      const int col = n0 + wn * 64 + n * 16 + fr;
      bf16* C = Cg + (long)bz * sC;
#pragma unroll
      for (int r = 0; r < 4; ++r)
        C[(long)(row + r) * ldc + col] = (bf16)(acc[mf][n][r] * scale);
    }
  }
}

// =====================================================================
// gemm8: BM=256, BN=256, BK=64, 512 threads (8 waves 2Mx4N, wave-tile
// 128x64, B-frag cache), LDS 128K, 4 phases/tile, counted vmcnt(4),
// SINGLE barrier/phase, XCD-swizzled.  bf16 out + scale.  (QK)
// =====================================================================
__global__ __launch_bounds__(512, 2) void gemm8(
    const bf16* __restrict__ Ag, const bf16* __restrict__ Bg,
    bf16* __restrict__ Cg,
    long lda, long ldb, long ldc,
    long sA, long sB, long sC, int K, float scale)
{
  constexpr int BUFSZ = 65536;
  __shared__ alignas(16) char lds[2 * BUFSZ];
  int bx, by, bz;
  xcd_swizzle(bx, by, bz);
  const int tid = threadIdx.x;
  const int l = tid & 63;
  const int wv = tid >> 6;
  const int fr = l & 15;
  const int kch = l >> 4;
  const int m0 = by * 256;
  const int n0 = bx * 256;
  const bf16* Ab = Ag + (long)bz * sA;
  const bf16* Bb = Bg + (long)bz * sB;

  const int wm = wv >> 2;
  const int wn = wv & 3;

  const int a_rd = fr * 128 + (((wm * 4 + kch) ^ (fr & 7)) << 4);
  const int b_rd = (wn & 1) * 8192 + fr * 128 + ((((wn >> 1) * 4 + kch) ^ (fr & 7)) << 4);

  const int se = (tid & 7) ^ ((tid >> 3) & 7);
  const int s_row = (se >> 2) * 128 + (tid >> 3);
  const int s_k = (se & 3) * 8;
  const int wb16 = (tid & 448) * 16;

  const int NT = K >> 6;
  f32x4 acc[8][4] = {};

  auto stageA = [&](int tile, int kh, int buf) {
#pragma unroll
    for (int rd = 0; rd < 2; ++rd)
      gload_lds16(Ab + (long)(m0 + s_row + rd * 64) * lda + tile * 64 + kh * 32 + s_k,
                  lds + buf * BUFSZ + kh * 16384 + rd * 8192 + wb16);
  };
  auto stageB = [&](int tile, int kh, int buf) {
#pragma unroll
    for (int rd = 0; rd < 2; ++rd)
      gload_lds16(Bb + (long)(n0 + s_row + rd * 64) * ldb + tile * 64 + kh * 32 + s_k,
                  lds + buf * BUFSZ + 32768 + kh * 16384 + rd * 8192 + wb16);
  };

  stageA(0, 0, 0); stageB(0, 0, 0); stageA(0, 1, 0); stageB(0, 1, 0);
  stageA(min(1, NT - 1), 0, 1); stageB(min(1, NT - 1), 0, 1);
  asm volatile("s_waitcnt vmcnt(4)" ::: "memory");
  __builtin_amdgcn_sched_barrier(0);
  __builtin_amdgcn_s_barrier();

  for (int t = 0; t < NT; ++t) {
    const char* bufA = lds + (t & 1) * BUFSZ;
    const char* bufB = bufA + 32768;
    const int t1 = min(t + 1, NT - 1);
    const int t2 = min(t + 2, NT - 1);
    const int nb = (t & 1) ^ 1;
    const int cur = t & 1;

    bf16x8 bfg[4], af[4];
    // P1
    stageA(t1, 1, nb);
#pragma unroll
    for (int n = 0; n < 4; ++n) bfg[n] = *(const bf16x8*)(bufB + n * 2048 + b_rd);
#pragma unroll
    for (int m = 0; m < 4; ++m) af[m] = *(const bf16x8*)(bufA + m * 2048 + a_rd);
    __builtin_amdgcn_s_setprio(1);
#pragma unroll
    for (int m = 0; m < 4; ++m)
#pragma unroll
      for (int n = 0; n < 4; ++n)
        acc[m][n] = __builtin_amdgcn_mfma_f32_16x16x32_bf16(af[m], bfg[n], acc[m][n], 0, 0, 0);
    __builtin_amdgcn_s_setprio(0);
    __builtin_amdgcn_s_barrier();
    // P2
    stageB(t1, 1, nb);
#pragma unroll
    for (int m = 0; m < 4; ++m) af[m] = *(const bf16x8*)(bufA + 8192 + m * 2048 + a_rd);
    __builtin_amdgcn_s_setprio(1);
#pragma unroll
    for (int m = 0; m < 4; ++m)
#pragma unroll
      for (int n = 0; n < 4; ++n)
        acc[4 + m][n] = __builtin_amdgcn_mfma_f32_16x16x32_bf16(af[m], bfg[n], acc[4 + m][n], 0, 0, 0);
    __builtin_amdgcn_s_setprio(0);
    __builtin_amdgcn_s_barrier();
    // P3
    stageA(t2, 0, cur);
#pragma unroll
    for (int n = 0; n < 4; ++n) bfg[n] = *(const bf16x8*)(bufB + 16384 + n * 2048 + b_rd);
#pragma unroll
    for (int m = 0; m < 4; ++m) af[m] = *(const bf16x8*)(bufA + 16384 + m * 2048 + a_rd);
    __builtin_amdgcn_s_setprio(1);
#pragma unroll
    for (int m = 0; m < 4; ++m)
#pragma unroll
      for (int n = 0; n < 4; ++n)
        acc[m][n] = __builtin_amdgcn_mfma_f32_16x16x32_bf16(af[m], bfg[n], acc[m][n], 0, 0, 0);
    __builtin_amdgcn_s_setprio(0);
    __builtin_amdgcn_s_barrier();
    // P4
    stageB(t2, 0, cur);
#pragma unroll
    for (int m = 0; m < 4; ++m) af[m] = *(const bf16x8*)(bufA + 16384 + 8192 + m * 2048 + a_rd);
    __builtin_amdgcn_s_setprio(1);
#pragma unroll
    for (int m = 0; m < 4; ++m)
#pragma unroll
      for (int n = 0; n < 4; ++n)
        acc[4 + m][n] = __builtin_amdgcn_mfma_f32_16x16x32_bf16(af[m], bfg[n], acc[4 + m][n], 0, 0, 0);
    __builtin_amdgcn_s_setprio(0);
    asm volatile("s_waitcnt vmcnt(4)" ::: "memory");
    __builtin_amdgcn_sched_barrier(0);
    __builtin_amdgcn_s_barrier();
  }
  asm volatile("s_waitcnt vmcnt(0)" ::: "memory");

#pragma unroll
  for (int mf = 0; mf < 8; ++mf) {
    const int row = m0 + wm * 128 + (mf >> 2) * 64 + (mf & 3) * 16 + (l >> 4) * 4;
#pragma unroll
    for (int n = 0; n < 4; ++n) {
      const int col = n0 + wn * 64 + n * 16 + fr;
      bf16* C = Cg + (long)bz * sC;
#pragma unroll
      for (int r = 0; r < 4; ++r)
        C[(long)(row + r) * ldc + col] = (bf16)(acc[mf][n][r] * scale);
    }
  }
}

// =====================================================================
// gemm128: BM=256, BN=128, BK=64, 512 threads (8 waves 2Mx4N, wave-tile
// 128x32, B-frag cache), 4 phases/tile, vmcnt(3), single barrier/phase,
// LDS 96K, XCD-swizzled.  ldb=2048.  Normal stores.
// MODE 0 (projV): bf16 out transposed into Vt[b][d][s] (bf16x4 along s).
// MODE 1 (PV):    fp32 out rows [s][d].
// =====================================================================
template <int MODE>
__global__ __launch_bounds__(512, 2) void gemm128(
    const bf16* __restrict__ Ag, const bf16* __restrict__ Bg,
    void* __restrict__ Cg,
    long sA, long sB, int K)
{
  constexpr int BUFSZ = 49152;
  __shared__ alignas(16) char lds[2 * BUFSZ];
  int bx, by, bz;
  xcd_swizzle(bx, by, bz);
  const int tid = threadIdx.x;
  const int l = tid & 63;
  const int wv = tid >> 6;
  const int wm = wv >> 2;
  const int wn = wv & 3;
  const int fr = l & 15;
  const int kch = l >> 4;
  const int m0 = by * 256;
  const int n0 = bx * 128;
  const bf16* Ab = Ag + (long)bz * sA;
  const bf16* Bb = Bg + (long)bz * sB;

  const int a_rd = fr * 128 + (((wm * 4 + kch) ^ (fr & 7)) << 4);
  int b_off[2];
#pragma unroll
  for (int n = 0; n < 2; ++n)
    b_off[n] = 32768 + ((wn & 1) * 32 + n * 16 + fr) * 128 +
               ((((wn >> 1) * 4 + kch) ^ (fr & 7)) << 4);

  const int se = (tid & 7) ^ ((tid >> 3) & 7);
  const int s_rowA = (se >> 2) * 128 + (tid >> 3);
  const int s_rowB = (se >> 2) * 64 + (tid >> 3);
  const int s_k = (se & 3) * 8;
  const int wb16 = (tid & 448) * 16;

  const int NT = K >> 6;
  f32x4 acc[8][2] = {};

  auto stageA = [&](int tile, int kh, int buf) {
#pragma unroll
    for (int rd = 0; rd < 2; ++rd)
      gload_lds16(Ab + (long)(m0 + s_rowA + rd * 64) * 2048 + tile * 64 + kh * 32 + s_k,
                  lds + buf * BUFSZ + kh * 16384 + rd * 8192 + wb16);
  };
  auto stageB = [&](int tile, int kh, int buf) {
    gload_lds16(Bb + (long)(n0 + s_rowB) * 2048 + tile * 64 + kh * 32 + s_k,
                lds + buf * BUFSZ + 32768 + kh * 8192 + wb16);
  };

  stageA(0, 0, 0); stageB(0, 0, 0); stageA(0, 1, 0); stageB(0, 1, 0);
  stageA(min(1, NT - 1), 0, 1); stageB(min(1, NT - 1), 0, 1);
  asm volatile("s_waitcnt vmcnt(3)" ::: "memory");
  __builtin_amdgcn_sched_barrier(0);
  __builtin_amdgcn_s_barrier();

  for (int t = 0; t < NT; ++t) {
    const char* bufA = lds + (t & 1) * BUFSZ;
    const int t1 = min(t + 1, NT - 1);
    const int t2 = min(t + 2, NT - 1);
    const int nb = (t & 1) ^ 1;
    const int cur = t & 1;

    bf16x8 bfg[2], af[4];
    // P1
    stageA(t1, 1, nb);
#pragma unroll
    for (int n = 0; n < 2; ++n) bfg[n] = *(const bf16x8*)(bufA + b_off[n]);
#pragma unroll
    for (int m = 0; m < 4; ++m) af[m] = *(const bf16x8*)(bufA + m * 2048 + a_rd);
    __builtin_amdgcn_s_setprio(1);
#pragma unroll
    for (int m = 0; m < 4; ++m)
#pragma unroll
      for (int n = 0; n < 2; ++n)
        acc[m][n] = __builtin_amdgcn_mfma_f32_16x16x32_bf16(af[m], bfg[n], acc[m][n], 0, 0, 0);
    __builtin_amdgcn_s_setprio(0);
    __builtin_amdgcn_s_barrier();
    // P2
    stageB(t1, 1, nb);
#pragma unroll
    for (int m = 0; m < 4; ++m) af[m] = *(const bf16x8*)(bufA + 8192 + m * 2048 + a_rd);
    __builtin_amdgcn_s_setprio(1);
#pragma unroll
    for (int m = 0; m < 4; ++m)
#pragma unroll
      for (int n = 0; n < 2; ++n)
        acc[4 + m][n] = __builtin_amdgcn_mfma_f32_16x16x32_bf16(af[m], bfg[n], acc[4 + m][n], 0, 0, 0);
    __builtin_amdgcn_s_setprio(0);
    __builtin_amdgcn_s_barrier();
    // P3
    stageA(t2, 0, cur);
#pragma unroll
    for (int n = 0; n < 2; ++n) bfg[n] = *(const bf16x8*)(bufA + 8192 + b_off[n]);
#pragma unroll
    for (int m = 0; m < 4; ++m) af[m] = *(const bf16x8*)(bufA + 16384 + m * 2048 + a_rd);
    __builtin_amdgcn_s_setprio(1);
#pragma unroll
    for (int m = 0; m < 4; ++m)
#pragma unroll
      for (int n = 0; n < 2; ++n)
        acc[m][n] = __builtin_amdgcn_mfma_f32_16x16x32_bf16(af[m], bfg[n], acc[m][n], 0, 0, 0);
    __builtin_amdgcn_s_setprio(0);
    __builtin_amdgcn_s_barrier();
    // P4
    stageB(t2, 0, cur);
#pragma unroll
    for (int m = 0; m < 4; ++m) af[m] = *(const bf16x8*)(bufA + 16384 + 8192 + m * 2048 + a_rd);
    __builtin_amdgcn_s_setprio(1);
#pragma unroll
    for (int m = 0; m < 4; ++m)
#pragma unroll
      for (int n = 0; n < 2; ++n)
        acc[4 + m][n] = __builtin_amdgcn_mfma_f32_16x16x32_bf16(af[m], bfg[n], acc[4 + m][n], 0, 0, 0);
    __builtin_amdgcn_s_setprio(0);
    asm volatile("s_waitcnt vmcnt(3)" ::: "memory");
    __builtin_amdgcn_sched_barrier(0);
    __builtin_amdgcn_s_barrier();
  }
  asm volatile("s_waitcnt vmcnt(0)" ::: "memory");

#pragma unroll
  for (int mf = 0; mf < 8; ++mf) {
    const int row = m0 + wm * 128 + (mf >> 2) * 64 + (mf & 3) * 16 + (l >> 4) * 4;
#pragma unroll
    for (int n = 0; n < 2; ++n) {
      const int col = n0 + wn * 32 + n * 16 + fr;
      if constexpr (MODE == 0) {
        bf16* Vt = (bf16*)Cg;
        bf16x4 pk;
#pragma unroll
        for (int r = 0; r < 4; ++r) pk[r] = (bf16)acc[mf][n][r];
        *(bf16x4*)(Vt + (long)bz * 2097152 + (long)col * 2048 + row) = pk;
      } else {
        float* C = (float*)Cg + (long)bz * 2097152;
#pragma unroll
        for (int r = 0; r < 4; ++r)
          C[(long)(row + r) * 1024 + col] = acc[mf][n][r];
      }
    }
  }
}

// ---------------- row softmax, XCD-aligned row mapping ----------------
__global__ __launch_bounds__(256) void softmax_k(const bf16* __restrict__ Sm,
                                                 bf16* __restrict__ P, int cols) {
  __shared__ float red[8];
  const int b = blockIdx.x;
  const long row = (long)(b & 7) * 1024 + (b >> 3);
  const bf16* sr = Sm + row * (long)cols;
  bf16* pr = P + row * (long)cols;
  const int t = threadIdx.x;
  bf16x8 v = *(const bf16x8*)(sr + t * 8);
  float e[8];
#pragma unroll
  for (int j = 0; j < 8; ++j) e[j] = (float)v[j];
  float m = e[0];
#pragma unroll
  for (int j = 1; j < 8; ++j) m = fmaxf(m, e[j]);
#pragma unroll
  for (int o = 32; o; o >>= 1) m = fmaxf(m, __shfl_xor(m, o));
  if ((t & 63) == 0) red[t >> 6] = m;
  __syncthreads();
  m = fmaxf(fmaxf(red[0], red[1]), fmaxf(red[2], red[3]));
  float s = 0.f;
#pragma unroll
  for (int j = 0; j < 8; ++j) { e[j] = __expf(e[j] - m); s += e[j]; }
#pragma unroll
  for (int o = 32; o; o >>= 1) s += __shfl_xor(s, o);
  if ((t & 63) == 0) red[4 + (t >> 6)] = s;
  __syncthreads();
  s = red[4] + red[5] + red[6] + red[7];
  const float inv = 1.0f / s;
  bf16x8 o8;
#pragma unroll
  for (int j = 0; j < 8; ++j) o8[j] = (bf16)(e[j] * inv);
  *(bf16x8*)(pr + t * 8) = o8;
}

extern "C" void kernel_launch(void* const* d_in, const int* in_sizes, int n_in,
                              void* d_out, int out_size, void* d_ws, size_t ws_size,
                              hipStream_t stream) {
  const float* x  = (const float*)d_in[0];
  const float* Wq = (const float*)d_in[1];
  const float* Wk = (const float*)d_in[2];
  const float* Wv = (const float*)d_in[3];
  float* out = (float*)d_out;

  // workspace (83.9 MB used):
  //  [0, 33.55M)        QKbuf bf16 [8192][2048]  -> later P (softmax out)
  //  [33.55M, 50.33M)   Vt bf16 [4][1024][2048]  (written by projV)
  //  [50.33M, 83.89M)   xb2 bf16 [8192][2048] (x + interleaved W) -> scb
  char* ws = (char*)d_ws;
  bf16* QKbuf = (bf16*)(ws);
  bf16* P     = (bf16*)(ws);
  bf16* Vt    = (bf16*)(ws + 33554432);
  bf16* scb   = (bf16*)(ws + 50331648);
  bf16* xb2   = (bf16*)(ws + 50331648);

  dim3 b256(256, 1, 1), b512(512, 1, 1);

  // 1) conversion: x -> xb2 cols 0-1023 (XCD-aligned), W -> xb2 pad halves
  cvt_all<<<2048, b256, 0, stream>>>(x, Wq, Wk, Wv, xb2);

  // 2a) Q/K proj — gemm8b TLP experiment (2 blocks/CU, 16 waves/CU)
  gemm8b<<<dim3(8, 8, 4), b512, 0, stream>>>(
      xb2, xb2 + 1024, QKbuf, 2048, 2048, 2048,
      4194304, 0, 4194304, 1024, 1.f);

  // 2b) V proj transposed into Vt
  gemm128<0><<<dim3(8, 8, 4), b512, 0, stream>>>(
      xb2, xb2 + 1024 + (long)2048 * 2048, Vt, 4194304, 0, 1024);

  // 3) scores = Q @ K^T / 32 -> bf16 (gemm8, unchanged control)
  gemm8<<<dim3(8, 8, 4), b512, 0, stream>>>(
      QKbuf, QKbuf + 1024, scb, 2048, 2048, 2048,
      4194304, 4194304, 4194304, 1024, 0.03125f);

  // 4) softmax (XCD-aligned rows) -> bf16 P
  softmax_k<<<8192, b256, 0, stream>>>(scb, P, 2048);

  // 5) out = P @ Vt^T
  gemm128<1><<<dim3(8, 8, 4), b512, 0, stream>>>(
      P, Vt, out, 4194304, 2097152, 2048);
}

// Round 24
// 162.884 us; speedup vs baseline: 2.1080x; 2.1080x over previous
//
#include <hip/hip_runtime.h>
#include <stdint.h>

typedef __bf16 bf16;
typedef __bf16 bf16x8 __attribute__((ext_vector_type(8)));
typedef __bf16 bf16x4 __attribute__((ext_vector_type(4)));
typedef float f32x4 __attribute__((ext_vector_type(4)));

__device__ inline void gload_lds16(const void* g, void* l) {
  __builtin_amdgcn_global_load_lds(
      (__attribute__((address_space(1))) void*)g,
      (__attribute__((address_space(3))) void*)l, 16, 0, 0);
}

// XCD-aware bijective swizzle (T1).  Requires nwg % 8 == 0.
__device__ inline void xcd_swizzle(int& bx, int& by, int& bz) {
  const int gx = gridDim.x, gy = gridDim.y;
  int lin = blockIdx.x + gx * (blockIdx.y + gy * blockIdx.z);
  const int nwg = gx * gy * gridDim.z;
  lin = (lin & 7) * (nwg >> 3) + (lin >> 3);
  bx = lin % gx;
  const int tmp = lin / gx;
  by = tmp % gy;
  bz = tmp / gy;
}

// ---------------- fp32 -> bf16 conversion ----------------
// xb2: [8192][2048] bf16.  Cols 0-1023: x rows (XCD-aligned ownership).
// Cols 1024-2047: W row j (packed [Wq;Wk;Wv], j<3072) interleaved.
__global__ __launch_bounds__(256) void cvt_all(
    const float* __restrict__ x, const float* __restrict__ wq,
    const float* __restrict__ wk, const float* __restrict__ wv,
    bf16* __restrict__ xb2) {
  const int b = blockIdx.x;
  const int t = threadIdx.x;
  const int xcd = b & 7, j = b >> 3;
#pragma unroll
  for (int k = 0; k < 4; ++k) {
    const int row = xcd * 1024 + j + 256 * k;
    float4 v = ((const float4*)x)[(long)row * 256 + t];
    bf16x4 o;
    o[0] = (bf16)v.x; o[1] = (bf16)v.y; o[2] = (bf16)v.z; o[3] = (bf16)v.w;
    *(bf16x4*)(xb2 + ((long)row << 11) + t * 4) = o;
  }
  for (long p = (long)b * 256 + t; p < 786432; p += 524288) {
    const int w = (int)(p >> 18);
    const int off = (int)(p & 262143);
    const float* src = (w == 0) ? wq : ((w == 1) ? wk : wv);
    const int row = off >> 8, c4 = off & 255;
    float4 v = ((const float4*)src)[off];
    bf16x4 o;
    o[0] = (bf16)v.x; o[1] = (bf16)v.y; o[2] = (bf16)v.z; o[3] = (bf16)v.w;
    *(bf16x4*)(xb2 + ((long)(w * 1024 + row) << 11) + 1024 + c4 * 4) = o;
  }
}

// =====================================================================
// gemm8: BM=256, BN=256, BK=64, 512 threads (8 waves 2Mx4N, wave-tile
// 128x64, B-frag cache), LDS 128K, 4 phases/tile, counted vmcnt(4),
// SINGLE barrier/phase, XCD-swizzled.  bf16 out + scale, normal stores.
// Used for projQK (B = xb2 pad halves, sB=0) and QK.
// =====================================================================
__global__ __launch_bounds__(512, 2) void gemm8(
    const bf16* __restrict__ Ag, const bf16* __restrict__ Bg,
    bf16* __restrict__ Cg,
    long lda, long ldb, long ldc,
    long sA, long sB, long sC, int K, float scale)
{
  constexpr int BUFSZ = 65536;
  __shared__ alignas(16) char lds[2 * BUFSZ];
  int bx, by, bz;
  xcd_swizzle(bx, by, bz);
  const int tid = threadIdx.x;
  const int l = tid & 63;
  const int wv = tid >> 6;
  const int fr = l & 15;
  const int kch = l >> 4;
  const int m0 = by * 256;
  const int n0 = bx * 256;
  const bf16* Ab = Ag + (long)bz * sA;
  const bf16* Bb = Bg + (long)bz * sB;

  const int wm = wv >> 2;
  const int wn = wv & 3;

  const int a_rd = fr * 128 + (((wm * 4 + kch) ^ (fr & 7)) << 4);
  const int b_rd = (wn & 1) * 8192 + fr * 128 + ((((wn >> 1) * 4 + kch) ^ (fr & 7)) << 4);

  const int se = (tid & 7) ^ ((tid >> 3) & 7);
  const int s_row = (se >> 2) * 128 + (tid >> 3);
  const int s_k = (se & 3) * 8;
  const int wb16 = (tid & 448) * 16;

  const int NT = K >> 6;
  f32x4 acc[8][4] = {};

  auto stageA = [&](int tile, int kh, int buf) {
#pragma unroll
    for (int rd = 0; rd < 2; ++rd)
      gload_lds16(Ab + (long)(m0 + s_row + rd * 64) * lda + tile * 64 + kh * 32 + s_k,
                  lds + buf * BUFSZ + kh * 16384 + rd * 8192 + wb16);
  };
  auto stageB = [&](int tile, int kh, int buf) {
#pragma unroll
    for (int rd = 0; rd < 2; ++rd)
      gload_lds16(Bb + (long)(n0 + s_row + rd * 64) * ldb + tile * 64 + kh * 32 + s_k,
                  lds + buf * BUFSZ + 32768 + kh * 16384 + rd * 8192 + wb16);
  };

  stageA(0, 0, 0); stageB(0, 0, 0); stageA(0, 1, 0); stageB(0, 1, 0);
  stageA(min(1, NT - 1), 0, 1); stageB(min(1, NT - 1), 0, 1);
  asm volatile("s_waitcnt vmcnt(4)" ::: "memory");
  __builtin_amdgcn_sched_barrier(0);
  __builtin_amdgcn_s_barrier();

  for (int t = 0; t < NT; ++t) {
    const char* bufA = lds + (t & 1) * BUFSZ;
    const char* bufB = bufA + 32768;
    const int t1 = min(t + 1, NT - 1);
    const int t2 = min(t + 2, NT - 1);
    const int nb = (t & 1) ^ 1;
    const int cur = t & 1;

    bf16x8 bfg[4], af[4];
    // P1
    stageA(t1, 1, nb);
#pragma unroll
    for (int n = 0; n < 4; ++n) bfg[n] = *(const bf16x8*)(bufB + n * 2048 + b_rd);
#pragma unroll
    for (int m = 0; m < 4; ++m) af[m] = *(const bf16x8*)(bufA + m * 2048 + a_rd);
    __builtin_amdgcn_s_setprio(1);
#pragma unroll
    for (int m = 0; m < 4; ++m)
#pragma unroll
      for (int n = 0; n < 4; ++n)
        acc[m][n] = __builtin_amdgcn_mfma_f32_16x16x32_bf16(af[m], bfg[n], acc[m][n], 0, 0, 0);
    __builtin_amdgcn_s_setprio(0);
    __builtin_amdgcn_s_barrier();
    // P2
    stageB(t1, 1, nb);
#pragma unroll
    for (int m = 0; m < 4; ++m) af[m] = *(const bf16x8*)(bufA + 8192 + m * 2048 + a_rd);
    __builtin_amdgcn_s_setprio(1);
#pragma unroll
    for (int m = 0; m < 4; ++m)
#pragma unroll
      for (int n = 0; n < 4; ++n)
        acc[4 + m][n] = __builtin_amdgcn_mfma_f32_16x16x32_bf16(af[m], bfg[n], acc[4 + m][n], 0, 0, 0);
    __builtin_amdgcn_s_setprio(0);
    __builtin_amdgcn_s_barrier();
    // P3
    stageA(t2, 0, cur);
#pragma unroll
    for (int n = 0; n < 4; ++n) bfg[n] = *(const bf16x8*)(bufB + 16384 + n * 2048 + b_rd);
#pragma unroll
    for (int m = 0; m < 4; ++m) af[m] = *(const bf16x8*)(bufA + 16384 + m * 2048 + a_rd);
    __builtin_amdgcn_s_setprio(1);
#pragma unroll
    for (int m = 0; m < 4; ++m)
#pragma unroll
      for (int n = 0; n < 4; ++n)
        acc[m][n] = __builtin_amdgcn_mfma_f32_16x16x32_bf16(af[m], bfg[n], acc[m][n], 0, 0, 0);
    __builtin_amdgcn_s_setprio(0);
    __builtin_amdgcn_s_barrier();
    // P4
    stageB(t2, 0, cur);
#pragma unroll
    for (int m = 0; m < 4; ++m) af[m] = *(const bf16x8*)(bufA + 16384 + 8192 + m * 2048 + a_rd);
    __builtin_amdgcn_s_setprio(1);
#pragma unroll
    for (int m = 0; m < 4; ++m)
#pragma unroll
      for (int n = 0; n < 4; ++n)
        acc[4 + m][n] = __builtin_amdgcn_mfma_f32_16x16x32_bf16(af[m], bfg[n], acc[4 + m][n], 0, 0, 0);
    __builtin_amdgcn_s_setprio(0);
    asm volatile("s_waitcnt vmcnt(4)" ::: "memory");
    __builtin_amdgcn_sched_barrier(0);
    __builtin_amdgcn_s_barrier();
  }
  asm volatile("s_waitcnt vmcnt(0)" ::: "memory");

#pragma unroll
  for (int mf = 0; mf < 8; ++mf) {
    const int row = m0 + wm * 128 + (mf >> 2) * 64 + (mf & 3) * 16 + (l >> 4) * 4;
#pragma unroll
    for (int n = 0; n < 4; ++n) {
      const int col = n0 + wn * 64 + n * 16 + fr;
      bf16* C = Cg + (long)bz * sC;
#pragma unroll
      for (int r = 0; r < 4; ++r)
        C[(long)(row + r) * ldc + col] = (bf16)(acc[mf][n][r] * scale);
    }
  }
}

// =====================================================================
// gemm128: BM=256, BN=128, BK=64, 512 threads (8 waves 2Mx4N, wave-tile
// 128x32, B-frag cache), 4 phases/tile, vmcnt(3), single barrier/phase,
// LDS 96K, XCD-swizzled.  ldb=2048.  Normal stores.
// MODE 0 (projV): bf16 out transposed into Vt[b][d][s] (bf16x4 along s).
// MODE 1 (PV):    fp32 out rows [s][d].
// =====================================================================
template <int MODE>
__global__ __launch_bounds__(512, 2) void gemm128(
    const bf16* __restrict__ Ag, const bf16* __restrict__ Bg,
    void* __restrict__ Cg,
    long sA, long sB, int K)
{
  constexpr int BUFSZ = 49152;
  __shared__ alignas(16) char lds[2 * BUFSZ];
  int bx, by, bz;
  xcd_swizzle(bx, by, bz);
  const int tid = threadIdx.x;
  const int l = tid & 63;
  const int wv = tid >> 6;
  const int wm = wv >> 2;
  const int wn = wv & 3;
  const int fr = l & 15;
  const int kch = l >> 4;
  const int m0 = by * 256;
  const int n0 = bx * 128;
  const bf16* Ab = Ag + (long)bz * sA;
  const bf16* Bb = Bg + (long)bz * sB;

  const int a_rd = fr * 128 + (((wm * 4 + kch) ^ (fr & 7)) << 4);
  int b_off[2];
#pragma unroll
  for (int n = 0; n < 2; ++n)
    b_off[n] = 32768 + ((wn & 1) * 32 + n * 16 + fr) * 128 +
               ((((wn >> 1) * 4 + kch) ^ (fr & 7)) << 4);

  const int se = (tid & 7) ^ ((tid >> 3) & 7);
  const int s_rowA = (se >> 2) * 128 + (tid >> 3);
  const int s_rowB = (se >> 2) * 64 + (tid >> 3);
  const int s_k = (se & 3) * 8;
  const int wb16 = (tid & 448) * 16;

  const int NT = K >> 6;
  f32x4 acc[8][2] = {};

  auto stageA = [&](int tile, int kh, int buf) {
#pragma unroll
    for (int rd = 0; rd < 2; ++rd)
      gload_lds16(Ab + (long)(m0 + s_rowA + rd * 64) * 2048 + tile * 64 + kh * 32 + s_k,
                  lds + buf * BUFSZ + kh * 16384 + rd * 8192 + wb16);
  };
  auto stageB = [&](int tile, int kh, int buf) {
    gload_lds16(Bb + (long)(n0 + s_rowB) * 2048 + tile * 64 + kh * 32 + s_k,
                lds + buf * BUFSZ + 32768 + kh * 8192 + wb16);
  };

  stageA(0, 0, 0); stageB(0, 0, 0); stageA(0, 1, 0); stageB(0, 1, 0);
  stageA(min(1, NT - 1), 0, 1); stageB(min(1, NT - 1), 0, 1);
  asm volatile("s_waitcnt vmcnt(3)" ::: "memory");
  __builtin_amdgcn_sched_barrier(0);
  __builtin_amdgcn_s_barrier();

  for (int t = 0; t < NT; ++t) {
    const char* bufA = lds + (t & 1) * BUFSZ;
    const int t1 = min(t + 1, NT - 1);
    const int t2 = min(t + 2, NT - 1);
    const int nb = (t & 1) ^ 1;
    const int cur = t & 1;

    bf16x8 bfg[2], af[4];
    // P1
    stageA(t1, 1, nb);
#pragma unroll
    for (int n = 0; n < 2; ++n) bfg[n] = *(const bf16x8*)(bufA + b_off[n]);
#pragma unroll
    for (int m = 0; m < 4; ++m) af[m] = *(const bf16x8*)(bufA + m * 2048 + a_rd);
    __builtin_amdgcn_s_setprio(1);
#pragma unroll
    for (int m = 0; m < 4; ++m)
#pragma unroll
      for (int n = 0; n < 2; ++n)
        acc[m][n] = __builtin_amdgcn_mfma_f32_16x16x32_bf16(af[m], bfg[n], acc[m][n], 0, 0, 0);
    __builtin_amdgcn_s_setprio(0);
    __builtin_amdgcn_s_barrier();
    // P2
    stageB(t1, 1, nb);
#pragma unroll
    for (int m = 0; m < 4; ++m) af[m] = *(const bf16x8*)(bufA + 8192 + m * 2048 + a_rd);
    __builtin_amdgcn_s_setprio(1);
#pragma unroll
    for (int m = 0; m < 4; ++m)
#pragma unroll
      for (int n = 0; n < 2; ++n)
        acc[4 + m][n] = __builtin_amdgcn_mfma_f32_16x16x32_bf16(af[m], bfg[n], acc[4 + m][n], 0, 0, 0);
    __builtin_amdgcn_s_setprio(0);
    __builtin_amdgcn_s_barrier();
    // P3
    stageA(t2, 0, cur);
#pragma unroll
    for (int n = 0; n < 2; ++n) bfg[n] = *(const bf16x8*)(bufA + 8192 + b_off[n]);
#pragma unroll
    for (int m = 0; m < 4; ++m) af[m] = *(const bf16x8*)(bufA + 16384 + m * 2048 + a_rd);
    __builtin_amdgcn_s_setprio(1);
#pragma unroll
    for (int m = 0; m < 4; ++m)
#pragma unroll
      for (int n = 0; n < 2; ++n)
        acc[m][n] = __builtin_amdgcn_mfma_f32_16x16x32_bf16(af[m], bfg[n], acc[m][n], 0, 0, 0);
    __builtin_amdgcn_s_setprio(0);
    __builtin_amdgcn_s_barrier();
    // P4
    stageB(t2, 0, cur);
#pragma unroll
    for (int m = 0; m < 4; ++m) af[m] = *(const bf16x8*)(bufA + 16384 + 8192 + m * 2048 + a_rd);
    __builtin_amdgcn_s_setprio(1);
#pragma unroll
    for (int m = 0; m < 4; ++m)
#pragma unroll
      for (int n = 0; n < 2; ++n)
        acc[4 + m][n] = __builtin_amdgcn_mfma_f32_16x16x32_bf16(af[m], bfg[n], acc[4 + m][n], 0, 0, 0);
    __builtin_amdgcn_s_setprio(0);
    asm volatile("s_waitcnt vmcnt(3)" ::: "memory");
    __builtin_amdgcn_sched_barrier(0);
    __builtin_amdgcn_s_barrier();
  }
  asm volatile("s_waitcnt vmcnt(0)" ::: "memory");

#pragma unroll
  for (int mf = 0; mf < 8; ++mf) {
    const int row = m0 + wm * 128 + (mf >> 2) * 64 + (mf & 3) * 16 + (l >> 4) * 4;
#pragma unroll
    for (int n = 0; n < 2; ++n) {
      const int col = n0 + wn * 32 + n * 16 + fr;
      if constexpr (MODE == 0) {
        bf16* Vt = (bf16*)Cg;
        bf16x4 pk;
#pragma unroll
        for (int r = 0; r < 4; ++r) pk[r] = (bf16)acc[mf][n][r];
        *(bf16x4*)(Vt + (long)bz * 2097152 + (long)col * 2048 + row) = pk;
      } else {
        float* C = (float*)Cg + (long)bz * 2097152;
#pragma unroll
        for (int r = 0; r < 4; ++r)
          C[(long)(row + r) * 1024 + col] = acc[mf][n][r];
      }
    }
  }
}

// ---------------- row softmax, XCD-aligned row mapping ----------------
__global__ __launch_bounds__(256) void softmax_k(const bf16* __restrict__ Sm,
                                                 bf16* __restrict__ P, int cols) {
  __shared__ float red[8];
  const int b = blockIdx.x;
  const long row = (long)(b & 7) * 1024 + (b >> 3);
  const bf16* sr = Sm + row * (long)cols;
  bf16* pr = P + row * (long)cols;
  const int t = threadIdx.x;
  bf16x8 v = *(const bf16x8*)(sr + t * 8);
  float e[8];
#pragma unroll
  for (int j = 0; j < 8; ++j) e[j] = (float)v[j];
  float m = e[0];
#pragma unroll
  for (int j = 1; j < 8; ++j) m = fmaxf(m, e[j]);
#pragma unroll
  for (int o = 32; o; o >>= 1) m = fmaxf(m, __shfl_xor(m, o));
  if ((t & 63) == 0) red[t >> 6] = m;
  __syncthreads();
  m = fmaxf(fmaxf(red[0], red[1]), fmaxf(red[2], red[3]));
  float s = 0.f;
#pragma unroll
  for (int j = 0; j < 8; ++j) { e[j] = __expf(e[j] - m); s += e[j]; }
#pragma unroll
  for (int o = 32; o; o >>= 1) s += __shfl_xor(s, o);
  if ((t & 63) == 0) red[4 + (t >> 6)] = s;
  __syncthreads();
  s = red[4] + red[5] + red[6] + red[7];
  const float inv = 1.0f / s;
  bf16x8 o8;
#pragma unroll
  for (int j = 0; j < 8; ++j) o8[j] = (bf16)(e[j] * inv);
  *(bf16x8*)(pr + t * 8) = o8;
}

extern "C" void kernel_launch(void* const* d_in, const int* in_sizes, int n_in,
                              void* d_out, int out_size, void* d_ws, size_t ws_size,
                              hipStream_t stream) {
  const float* x  = (const float*)d_in[0];
  const float* Wq = (const float*)d_in[1];
  const float* Wk = (const float*)d_in[2];
  const float* Wv = (const float*)d_in[3];
  float* out = (float*)d_out;

  // workspace (83.9 MB used):
  //  [0, 33.55M)        QKbuf bf16 [8192][2048]  -> later P (softmax out)
  //  [33.55M, 50.33M)   Vt bf16 [4][1024][2048]  (written by projV)
  //  [50.33M, 83.89M)   xb2 bf16 [8192][2048] (x + interleaved W) -> scb
  char* ws = (char*)d_ws;
  bf16* QKbuf = (bf16*)(ws);
  bf16* P     = (bf16*)(ws);
  bf16* Vt    = (bf16*)(ws + 33554432);
  bf16* scb   = (bf16*)(ws + 50331648);
  bf16* xb2   = (bf16*)(ws + 50331648);

  dim3 b256(256, 1, 1), b512(512, 1, 1);

  // 1) conversion: x -> xb2 cols 0-1023 (XCD-aligned), W -> xb2 pad halves
  cvt_all<<<2048, b256, 0, stream>>>(x, Wq, Wk, Wv, xb2);

  // 2a) Q/K proj
  gemm8<<<dim3(8, 8, 4), b512, 0, stream>>>(
      xb2, xb2 + 1024, QKbuf, 2048, 2048, 2048,
      4194304, 0, 4194304, 1024, 1.f);

  // 2b) V proj transposed into Vt
  gemm128<0><<<dim3(8, 8, 4), b512, 0, stream>>>(
      xb2, xb2 + 1024 + (long)2048 * 2048, Vt, 4194304, 0, 1024);

  // 3) scores = Q @ K^T / 32 -> bf16
  gemm8<<<dim3(8, 8, 4), b512, 0, stream>>>(
      QKbuf, QKbuf + 1024, scb, 2048, 2048, 2048,
      4194304, 4194304, 4194304, 1024, 0.03125f);

  // 4) softmax (XCD-aligned rows) -> bf16 P
  softmax_k<<<8192, b256, 0, stream>>>(scb, P, 2048);

  // 5) out = P @ Vt^T
  gemm128<1><<<dim3(8, 8, 4), b512, 0, stream>>>(
      P, Vt, out, 4194304, 2097152, 2048);
}